// Round 2
// baseline (235.753 us; speedup 1.0000x reference)
//
#include <hip/hip_runtime.h>

#define SEQ    2048
#define DMODEL 512
#define NHEAD  8
#define HDIM   64
#define BATCH  4
#define NROWS  65536          // H*SEQ*BATCH scrambled q-rows
#define KSPLIT 2

#define LOG2E  1.4426950408889634f
#define QSCALE 0.18033688011112042f   // 0.125 * log2(e), folded into Q proj

typedef float f32x4  __attribute__((ext_vector_type(4)));
typedef float f32x16 __attribute__((ext_vector_type(16)));
typedef _Float16 h16x8 __attribute__((ext_vector_type(8)));
typedef _Float16 h16x2 __attribute__((ext_vector_type(2)));
typedef unsigned int u32x2 __attribute__((ext_vector_type(2)));

union U4H { uint4 u; h16x8 h; };
union U1H2 { unsigned int u; h16x2 h; };

static __device__ inline h16x2 pkrtz(float a, float b) {
    return __builtin_bit_cast(h16x2, __builtin_amdgcn_cvt_pkrtz(a, b));
}
static __device__ inline unsigned short f2h(float x) {
    _Float16 h = (_Float16)x;
    return __builtin_bit_cast(unsigned short, h);
}
// async 16B/lane global->LDS copy (lds base must be wave-uniform)
static __device__ inline void async_cp16(const void* g, void* l) {
    __builtin_amdgcn_global_load_lds(
        (const __attribute__((address_space(1))) unsigned int*)g,
        (__attribute__((address_space(3))) unsigned int*)l,
        16, 0, 0);
}

// ---------------------------------------------------------------------------
// Fused pre-pass (one dispatch, three independent jobs selected by block id):
//   [0,1024)        transpose-cast the four 512x512 weight mats -> f16 [n][k]
//   [1024,5120)     em = fp16(exp(mask)) permuted to the S^T C-layout order
//   [5120,11264)    fp32 -> fp16 cast of the three activation inputs
// ---------------------------------------------------------------------------
struct PrepArgs {
    const float *Wq, *Wk, *Wv, *Wo;
    unsigned short *WqT, *WkT, *WvT, *WoT;
    const float *mask; unsigned short *mp;
    const float *aq, *ak, *av;
    unsigned short *dq, *dk, *dv;
};

__global__ __launch_bounds__(256) void prepass(PrepArgs a) {
    const int bid = blockIdx.x;
    const int t = threadIdx.x;

    if (bid < 1024) {
        // ---- weight transpose-cast ----
        const int z = bid >> 8, y = (bid >> 4) & 15, x = bid & 15;
        const float* S; unsigned short* D;
        switch (z) {
            case 0: S = a.Wq; D = a.WqT; break;
            case 1: S = a.Wk; D = a.WkT; break;
            case 2: S = a.Wv; D = a.WvT; break;
            default: S = a.Wo; D = a.WoT; break;
        }
        __shared__ float T[32][33];
        const int r = t >> 3, c = (t & 7) * 4;
        const int k0 = x * 32, n0 = y * 32;
        float4 v = *(const float4*)&S[(size_t)(k0 + r) * DMODEL + n0 + c];
        T[r][c] = v.x; T[r][c + 1] = v.y; T[r][c + 2] = v.z; T[r][c + 3] = v.w;
        __syncthreads();
        ushort4 o;
        o.x = f2h(T[c + 0][r]); o.y = f2h(T[c + 1][r]);
        o.z = f2h(T[c + 2][r]); o.w = f2h(T[c + 3][r]);
        *(ushort4*)&D[(size_t)(n0 + r) * DMODEL + k0 + c] = o;
    } else if (bid < 1024 + 4096) {
        // ---- mask exp pre-pass ----
        int i = (bid - 1024) * 256 + t;             // float4 index
        int k = (i * 4) & (SEQ - 1);
        int q = (i * 4) >> 11;
        float4 v = ((const float4*)a.mask)[i];
        int kt = k >> 6, kl = k & 63;
        int mt = kl >> 5, g = (kl >> 3) & 3, hl = (kl >> 2) & 1;
        size_t base = ((size_t)kt * SEQ + q) * 64 + hl * 32 + mt * 16 + g * 4;
        ushort4 o;
        o.x = f2h(__builtin_amdgcn_exp2f(v.x * LOG2E));
        o.y = f2h(__builtin_amdgcn_exp2f(v.y * LOG2E));
        o.z = f2h(__builtin_amdgcn_exp2f(v.z * LOG2E));
        o.w = f2h(__builtin_amdgcn_exp2f(v.w * LOG2E));
        *(ushort4*)&a.mp[base] = o;
    } else {
        // ---- activation fp32 -> fp16 cast ----
        int u = bid - 5120;
        int z = u >> 11, blk = u & 2047;
        const float* S; unsigned short* D;
        switch (z) {
            case 0: S = a.aq; D = a.dq; break;
            case 1: S = a.ak; D = a.dk; break;
            default: S = a.av; D = a.dv; break;
        }
        size_t i = ((size_t)blk * 256 + t) * 8;
        float4 x = *(const float4*)&S[i];
        float4 y = *(const float4*)&S[i + 4];
        U1H2 p0, p1, p2, p3;
        p0.h = pkrtz(x.x, x.y); p1.h = pkrtz(x.z, x.w);
        p2.h = pkrtz(y.x, y.y); p3.h = pkrtz(y.z, y.w);
        *(uint4*)&D[i] = make_uint4(p0.u, p1.u, p2.u, p3.u);
    }
}

// ---------------------------------------------------------------------------
// GEMM core (f16 A): C[..][512] = A[..][512] @ Wt[512][512]^T + bias.
// 128x128 tile, BK=32, 256 thr = 4 waves, wave = 64m x 64n (4x4 MFMA 16x16x32).
// Double-buffered LDS, ONE barrier per K-step: stage k+1 issued before the
// ds_read+MFMA of k, so global_load_lds latency hides under compute.
// Both-sides XOR chunk swizzle -> frag reads land in the free 2-way case.
// EPI: 0 = f32 row-major, 1 = f16 row-major, 2 = f16 transposed per-head to
//      vT[((b*8+h)*64+dv)*SEQ + key]
// ---------------------------------------------------------------------------
template <int EPI>
static __device__ inline void gemm_core16(
    const unsigned short* __restrict__ Ab, const unsigned short* __restrict__ Bt,
    const float* __restrict__ bias, void* __restrict__ Cout, float oscale,
    int bm, int bn)
{
    __shared__ __align__(16) unsigned short As[2][128 * 32];
    __shared__ __align__(16) unsigned short Bs[2][128 * 32];

    const int t = threadIdx.x;
    const int lane = t & 63, w = t >> 6;
    const int wm = w >> 1, wn = w & 1;
    const int c = lane & 15, quad = lane >> 4;
    const int srow = lane >> 2;                      // row within 16-row group
    const int sck  = (lane & 3) ^ ((lane >> 3) & 3); // swizzled source chunk

    f32x4 acc[4][4] = {};

    // prologue: stage k0 = 0 into buffer 0
    #pragma unroll
    for (int i = 0; i < 2; i++) {
        int row = 32 * w + 16 * i + srow;
        async_cp16(Ab + (size_t)(bm + row) * DMODEL + sck * 8,
                   &As[0][(32 * w + 16 * i) * 32]);
        async_cp16(Bt + (size_t)(bn + row) * DMODEL + sck * 8,
                   &Bs[0][(32 * w + 16 * i) * 32]);
    }
    __syncthreads();

    const int slot8 = (quad ^ ((c >> 1) & 3)) * 8;

    for (int k0 = 0; k0 < DMODEL; k0 += 32) {
        const int cur = (k0 >> 5) & 1;
        // issue next-tile stage FIRST (targets buf cur^1; no hazard with reads)
        if (k0 + 32 < DMODEL) {
            #pragma unroll
            for (int i = 0; i < 2; i++) {
                int row = 32 * w + 16 * i + srow;
                async_cp16(Ab + (size_t)(bm + row) * DMODEL + k0 + 32 + sck * 8,
                           &As[cur ^ 1][(32 * w + 16 * i) * 32]);
                async_cp16(Bt + (size_t)(bn + row) * DMODEL + k0 + 32 + sck * 8,
                           &Bs[cur ^ 1][(32 * w + 16 * i) * 32]);
            }
        }
        U4H af[4], bf[4];
        #pragma unroll
        for (int mt = 0; mt < 4; mt++)
            af[mt].u = *(const uint4*)&As[cur][(wm * 64 + mt * 16 + c) * 32 + slot8];
        #pragma unroll
        for (int nt = 0; nt < 4; nt++)
            bf[nt].u = *(const uint4*)&Bs[cur][(wn * 64 + nt * 16 + c) * 32 + slot8];
        #pragma unroll
        for (int mt = 0; mt < 4; mt++)
            #pragma unroll
            for (int nt = 0; nt < 4; nt++)
                acc[mt][nt] = __builtin_amdgcn_mfma_f32_16x16x32_f16(
                    af[mt].h, bf[nt].h, acc[mt][nt], 0, 0, 0);
        // one barrier/step: drains next-tile stage (vmcnt) + fences reads (lgkm)
        __syncthreads();
    }

    if (EPI == 2) {
        #pragma unroll
        for (int nt = 0; nt < 4; nt++) {
            int ng = bn + wn * 64 + nt * 16 + c;
            int h = ng >> 6, dv = ng & 63;
            float bv = bias[ng];
            #pragma unroll
            for (int mt = 0; mt < 4; mt++) {
                int mg0 = bm + wm * 64 + mt * 16 + quad * 4;
                int bb = mg0 >> 11, key0 = mg0 & (SEQ - 1);
                U1H2 lo, hi;
                lo.h = pkrtz(acc[mt][nt][0] + bv, acc[mt][nt][1] + bv);
                hi.h = pkrtz(acc[mt][nt][2] + bv, acc[mt][nt][3] + bv);
                *(uint2*)&((unsigned short*)Cout)[
                    ((size_t)(bb * NHEAD + h) * HDIM + dv) * SEQ + key0] =
                    make_uint2(lo.u, hi.u);
            }
        }
        return;
    }
    #pragma unroll
    for (int nt = 0; nt < 4; nt++) {
        int ng = bn + wn * 64 + nt * 16 + c;
        float bv = bias[ng];
        #pragma unroll
        for (int mt = 0; mt < 4; mt++) {
            #pragma unroll
            for (int r = 0; r < 4; r++) {
                int mg = bm + wm * 64 + mt * 16 + quad * 4 + r;
                float v = (acc[mt][nt][r] + bv) * oscale;
                if (EPI == 1)
                    ((unsigned short*)Cout)[(size_t)mg * DMODEL + ng] = f2h(v);
                else
                    ((float*)Cout)[(size_t)mg * DMODEL + ng] = v;
            }
        }
    }
}

struct QKVArgs {
    const unsigned short *A0, *A1, *A2;
    const unsigned short *W0, *W1, *W2;
    const float *b0, *b1, *b2;
    unsigned short *o0, *o1, *o2;
};

__global__ __launch_bounds__(256) void gemm_qkv(QKVArgs a) {
    if (blockIdx.z == 2)
        gemm_core16<2>(a.A2, a.W2, a.b2, a.o2, 1.0f, blockIdx.y * 128, blockIdx.x * 128);
    else if (blockIdx.z == 1)
        gemm_core16<1>(a.A1, a.W1, a.b1, a.o1, 1.0f, blockIdx.y * 128, blockIdx.x * 128);
    else
        gemm_core16<1>(a.A0, a.W0, a.b0, a.o0, QSCALE, blockIdx.y * 128, blockIdx.x * 128);
}

__global__ __launch_bounds__(256) void gemm_fin(
    const unsigned short* __restrict__ A, const unsigned short* __restrict__ W,
    const float* __restrict__ bias, float* __restrict__ C) {
    gemm_core16<0>(A, W, bias, C, 1.0f, blockIdx.y * 128, blockIdx.x * 128);
}

// ---------------------------------------------------------------------------
// Flash attention, 32x32x16 f16 MFMA, S^T trick, no-max softmax, K-SPLIT 2.
// This revision: 1D grid + XCD-aware decode. All 32 (b,head) blocks of a
// (qtile,split) combo get block ids congruent mod 8 -> same XCD -> the shared
// em tile (256 KB) becomes L2-resident instead of being replicated across all
// 8 XCD L2s (which pushed ~450 MB of re-reads to Infinity Cache). The 2
// q-tiles sharing each (bh,split) K/V panel are also co-XCD.
// ---------------------------------------------------------------------------
__global__ __launch_bounds__(256, 3) void attn5(
    const unsigned short* __restrict__ qb, const unsigned short* __restrict__ kb,
    const unsigned short* __restrict__ vT, const unsigned short* __restrict__ emp,
    unsigned short* __restrict__ Xp, float* __restrict__ Lp)
{
    __shared__ __align__(16) unsigned short Ks[2][64 * 64];
    __shared__ __align__(16) unsigned short Vs[2][64 * 64];

    const int t = threadIdx.x;            // 0..255
    const int lane = t & 63, w = t >> 6;  // 4 waves
    const int c32 = lane & 31, hl = lane >> 5;

    // XCD-aware block decode (round-robin bid%8 -> XCD):
    //   xcd = bid&7, slot = bid>>3 in [0,128): bh = slot&31, cidx = slot>>5
    //   combo c = cidx*8 + xcd in [0,32): qtile = c&15, split = c>>4
    const int bid = blockIdx.x;
    const int xcd = bid & 7, slot = bid >> 3;
    const int bh = slot & 31;
    const int comb = (slot >> 5) * 8 + xcd;
    const int split = comb >> 4;          // keys [split*1024, split*1024+1024)
    const int q0 = (comb & 15) * 128;
    const int b = bh >> 3, head = bh & 7;
    const int qg = q0 + w * 32 + c32;

    // hoisted Q B-frags (q pre-scaled by 0.125*log2e in projection)
    const unsigned short* qrow = qb + ((size_t)b * SEQ + qg) * DMODEL + head * HDIM;
    U4H Qf[4];
    #pragma unroll
    for (int s = 0; s < 4; s++)
        Qf[s].u = *(const uint4*)&qrow[s * 16 + hl * 8];

    const unsigned short* kgb = kb + (size_t)b * SEQ * DMODEL + head * HDIM
                              + (size_t)split * 1024 * DMODEL;
    const unsigned short* vgb = vT + (size_t)bh * HDIM * SEQ + split * 1024;

    // staging lane mapping: row-in-chunk = lane>>3, swizzled global chunk
    const int srow = lane >> 3;           // 0..7
    const int sch  = (lane & 7) ^ srow;   // logical feature/key chunk

    // issue tile 0 into buffer 0
    {
        #pragma unroll
        for (int i = 0; i < 2; i++) {
            int row = w * 16 + i * 8 + srow;
            async_cp16(&kgb[(size_t)row * DMODEL + sch * 8], &Ks[0][(w * 16 + i * 8) * 64]);
            async_cp16(&vgb[(size_t)row * SEQ + sch * 8],    &Vs[0][(w * 16 + i * 8) * 64]);
        }
    }

    // preload em for tile 0 (register prefetch pipeline)
    U4H e0, e1, e2, e3;
    {
        const unsigned short* mrow = emp + ((size_t)(split * 16) * SEQ + qg) * 64 + hl * 32;
        e0.u = *(const uint4*)&mrow[0];
        e1.u = *(const uint4*)&mrow[8];
        e2.u = *(const uint4*)&mrow[16];
        e3.u = *(const uint4*)&mrow[24];
    }

    f32x16 O0 = {}, O1 = {};
    float lsum = 0.f;
    const h16x2 one2 = {(_Float16)1.0f, (_Float16)1.0f};

    for (int kt = 0; kt < 1024 / 64; kt++) {
        const int p = kt & 1;
        __syncthreads();                  // buf[p] staged; buf[p^1] reads done

        // async stage tile kt+1 into the other buffer (in flight during compute)
        if (kt + 1 < 1024 / 64) {
            int k0n = (kt + 1) * 64;
            #pragma unroll
            for (int i = 0; i < 2; i++) {
                int row = w * 16 + i * 8 + srow;
                async_cp16(&kgb[(size_t)(k0n + row) * DMODEL + sch * 8],
                           &Ks[p ^ 1][(w * 16 + i * 8) * 64]);
                async_cp16(&vgb[(size_t)row * SEQ + k0n + sch * 8],
                           &Vs[p ^ 1][(w * 16 + i * 8) * 64]);
            }
        }

        // prefetch em for NEXT tile (used after the next barrier's vmcnt drain)
        U4H f0, f1, f2, f3;
        {
            int ktn = (kt + 1 < 1024 / 64) ? kt + 1 : kt;   // clamp: in-bounds, unused
            const unsigned short* mrow =
                emp + ((size_t)(split * 16 + ktn) * SEQ + qg) * 64 + hl * 32;
            f0.u = *(const uint4*)&mrow[0];
            f1.u = *(const uint4*)&mrow[8];
            f2.u = *(const uint4*)&mrow[16];
            f3.u = *(const uint4*)&mrow[24];
        }

        const unsigned short* Kp = Ks[p];
        const unsigned short* Vp = Vs[p];

        // ---- S^T = K.Q^T : 2 key-tiles x 4 feature-steps ----
        f32x16 S0 = {}, S1 = {};
        __builtin_amdgcn_s_setprio(1);
        #pragma unroll
        for (int s = 0; s < 4; s++) {
            int fc = 2 * s + hl;
            int sl = (fc ^ (c32 & 7)) * 8;
            U4H ka0, ka1;
            ka0.u = *(const uint4*)&Kp[c32 * 64 + sl];
            ka1.u = *(const uint4*)&Kp[(32 + c32) * 64 + sl];
            S0 = __builtin_amdgcn_mfma_f32_32x32x16_f16(ka0.h, Qf[s].h, S0, 0, 0, 0);
            S1 = __builtin_amdgcn_mfma_f32_32x32x16_f16(ka1.h, Qf[s].h, S1, 0, 0, 0);
        }
        __builtin_amdgcn_s_setprio(0);

        // ---- softmax: p = exp2(S) * em, f16 pack, l-accumulate via dot2 ----
        unsigned int Pf[4][4];
        #pragma unroll
        for (int mt = 0; mt < 2; mt++) {
            f32x16 S = mt ? S1 : S0;
            h16x8 ea = (mt ? e2 : e0).h;
            h16x8 eb = (mt ? e3 : e1).h;
            unsigned int u[4][2];
            #pragma unroll
            for (int jj = 0; jj < 8; jj++) {
                _Float16 exl = (jj < 4) ? ea[2 * jj]     : eb[2 * jj - 8];
                _Float16 exh = (jj < 4) ? ea[2 * jj + 1] : eb[2 * jj - 7];
                h16x2 ex = {exl, exh};
                h16x2 pk = pkrtz(__builtin_amdgcn_exp2f(S[2 * jj]),
                                 __builtin_amdgcn_exp2f(S[2 * jj + 1]));
                h16x2 pp = pk * ex;
#if __has_builtin(__builtin_amdgcn_fdot2)
                lsum = __builtin_amdgcn_fdot2(pp, one2, lsum, false);
#else
                lsum += (float)pp[0] + (float)pp[1];
#endif
                u[jj >> 1][jj & 1] = __builtin_bit_cast(unsigned int, pp);
            }
            // half-wave block exchange (C-layout -> PV B-operand layout)
#if __has_builtin(__builtin_amdgcn_permlane32_swap)
            u32x2 rA0 = __builtin_amdgcn_permlane32_swap(u[0][0], u[1][0], false, false);
            u32x2 rA1 = __builtin_amdgcn_permlane32_swap(u[0][1], u[1][1], false, false);
            u32x2 rB0 = __builtin_amdgcn_permlane32_swap(u[2][0], u[3][0], false, false);
            u32x2 rB1 = __builtin_amdgcn_permlane32_swap(u[2][1], u[3][1], false, false);
            Pf[2 * mt + 0][0] = rA0[0]; Pf[2 * mt + 0][1] = rA1[0];
            Pf[2 * mt + 0][2] = rA0[1]; Pf[2 * mt + 0][3] = rA1[1];
            Pf[2 * mt + 1][0] = rB0[0]; Pf[2 * mt + 1][1] = rB1[0];
            Pf[2 * mt + 1][2] = rB0[1]; Pf[2 * mt + 1][3] = rB1[1];
#else
            unsigned int sA0 = hl ? u[0][0] : u[1][0];
            unsigned int sA1 = hl ? u[0][1] : u[1][1];
            unsigned int sB0 = hl ? u[2][0] : u[3][0];
            unsigned int sB1 = hl ? u[2][1] : u[3][1];
            unsigned int rA0 = (unsigned)__shfl_xor((int)sA0, 32, 64);
            unsigned int rA1 = (unsigned)__shfl_xor((int)sA1, 32, 64);
            unsigned int rB0 = (unsigned)__shfl_xor((int)sB0, 32, 64);
            unsigned int rB1 = (unsigned)__shfl_xor((int)sB1, 32, 64);
            Pf[2 * mt + 0][0] = hl ? rA0 : u[0][0];
            Pf[2 * mt + 0][1] = hl ? rA1 : u[0][1];
            Pf[2 * mt + 0][2] = hl ? u[1][0] : rA0;
            Pf[2 * mt + 0][3] = hl ? u[1][1] : rA1;
            Pf[2 * mt + 1][0] = hl ? rB0 : u[2][0];
            Pf[2 * mt + 1][1] = hl ? rB1 : u[2][1];
            Pf[2 * mt + 1][2] = hl ? u[3][0] : rB0;
            Pf[2 * mt + 1][3] = hl ? u[3][1] : rB1;
#endif
        }

        // ---- O^T += V^T . P : 2 dv-tiles x 4 key-steps ----
        __builtin_amdgcn_s_setprio(1);
        #pragma unroll
        for (int s = 0; s < 4; s++) {
            int kc = 2 * s + hl;
            int sl = (kc ^ (c32 & 7)) * 8;
            U4H va0, va1, pu;
            va0.u = *(const uint4*)&Vp[c32 * 64 + sl];
            va1.u = *(const uint4*)&Vp[(32 + c32) * 64 + sl];
            pu.u = make_uint4(Pf[s][0], Pf[s][1], Pf[s][2], Pf[s][3]);
            O0 = __builtin_amdgcn_mfma_f32_32x32x16_f16(va0.h, pu.h, O0, 0, 0, 0);
            O1 = __builtin_amdgcn_mfma_f32_32x32x16_f16(va1.h, pu.h, O1, 0, 0, 0);
        }
        __builtin_amdgcn_s_setprio(0);

        // rotate em prefetch registers
        e0 = f0; e1 = f1; e2 = f2; e3 = f3;
    }

    // ---- epilogue: combine lane-halves' l, store UNNORMALIZED f16 partial ----
    lsum += __shfl_xor(lsum, 32, 64);
    const size_t j = ((size_t)head * SEQ + qg) * BATCH + b;
    unsigned short* xr = Xp + ((size_t)split * NROWS + j) * HDIM;
    #pragma unroll
    for (int mt = 0; mt < 2; mt++) {
        f32x16 Ov = mt ? O1 : O0;
        #pragma unroll
        for (int g = 0; g < 4; g++) {
            U1H2 lo, hi;
            lo.h = pkrtz(Ov[g * 4 + 0], Ov[g * 4 + 1]);
            hi.h = pkrtz(Ov[g * 4 + 2], Ov[g * 4 + 3]);
            uint2 st = make_uint2(lo.u, hi.u);
            *(uint2*)&xr[mt * 32 + 8 * g + 4 * hl] = st;
        }
    }
    if (hl == 0) Lp[split * NROWS + j] = lsum;
}

// ---------------------------------------------------------------------------
// Combine K-split partials: xb[j][dv] = (Sum_r Xp[r][j][dv]) / (Sum_r L[r][j])
// ---------------------------------------------------------------------------
__global__ __launch_bounds__(256) void combine_attn(
    const unsigned short* __restrict__ Xp, const float* __restrict__ Lp,
    unsigned short* __restrict__ xb)
{
    int i = blockIdx.x * 256 + threadIdx.x;
    int j = i >> 3, dc = (i & 7) * 8;
    U4H a, b;
    a.u = *(const uint4*)&Xp[(size_t)j * HDIM + dc];
    b.u = *(const uint4*)&Xp[((size_t)NROWS + j) * HDIM + dc];
    float inv = 1.0f / (Lp[j] + Lp[NROWS + j]);
    U4H o;
    #pragma unroll
    for (int p = 0; p < 4; p++) {
        float s0 = ((float)a.h[2 * p]     + (float)b.h[2 * p])     * inv;
        float s1 = ((float)a.h[2 * p + 1] + (float)b.h[2 * p + 1]) * inv;
        h16x2 pk = pkrtz(s0, s1);
        o.h[2 * p] = pk[0]; o.h[2 * p + 1] = pk[1];
    }
    *(uint4*)&xb[(size_t)j * HDIM + dc] = o.u;
}

// ---------------------------------------------------------------------------
extern "C" void kernel_launch(void* const* d_in, const int* in_sizes, int n_in,
                              void* d_out, int out_size, void* d_ws, size_t ws_size,
                              hipStream_t stream) {
    const float* query = (const float*)d_in[0];
    const float* key_  = (const float*)d_in[1];
    const float* value = (const float*)d_in[2];
    const float* mask  = (const float*)d_in[3];
    const float* Wq = (const float*)d_in[4];
    const float* bq = (const float*)d_in[5];
    const float* Wk = (const float*)d_in[6];
    const float* bk = (const float*)d_in[7];
    const float* Wv = (const float*)d_in[8];
    const float* bv = (const float*)d_in[9];
    const float* Wo = (const float*)d_in[10];
    const float* bo = (const float*)d_in[11];
    float* out = (float*)d_out;

    const size_t NP = (size_t)BATCH * SEQ * DMODEL;   // 4194304
    unsigned short* ws   = (unsigned short*)d_ws;
    unsigned short* qb16 = ws;
    unsigned short* kb16 = qb16 + NP;
    unsigned short* vT16 = kb16 + NP;
    unsigned short* xb16 = vT16 + NP;
    unsigned short* em16 = xb16 + NP;                 // SEQ*SEQ f16
    unsigned short* Xp16 = em16 + (size_t)SEQ * SEQ;  // KSPLIT*NROWS*64 f16 = 2*NP
    unsigned short* WqT  = Xp16 + (size_t)KSPLIT * NROWS * HDIM;
    unsigned short* WkT  = WqT + DMODEL * DMODEL;
    unsigned short* WvT  = WkT + DMODEL * DMODEL;
    unsigned short* WoT  = WvT + DMODEL * DMODEL;
    float* Lp = (float*)(WoT + DMODEL * DMODEL);      // KSPLIT*NROWS f32

    // f16 casts of Q/K/V inputs live in regions that are dead until attn/combine:
    unsigned short* q16 = xb16;
    unsigned short* k16 = Xp16;
    unsigned short* v16 = Xp16 + NP;

    PrepArgs pa;
    pa.Wq = Wq; pa.Wk = Wk; pa.Wv = Wv; pa.Wo = Wo;
    pa.WqT = WqT; pa.WkT = WkT; pa.WvT = WvT; pa.WoT = WoT;
    pa.mask = mask; pa.mp = em16;
    pa.aq = query; pa.ak = key_; pa.av = value;
    pa.dq = q16; pa.dk = k16; pa.dv = v16;
    prepass<<<dim3(1024 + 4096 + 6144), 256, 0, stream>>>(pa);

    QKVArgs qa;
    qa.A0 = q16;  qa.A1 = k16;  qa.A2 = v16;
    qa.W0 = WqT;  qa.W1 = WkT;  qa.W2 = WvT;
    qa.b0 = bq;   qa.b1 = bk;   qa.b2 = bv;
    qa.o0 = qb16; qa.o1 = kb16; qa.o2 = vT16;   // V written transposed
    gemm_qkv<<<dim3(DMODEL / 128, BATCH * SEQ / 128, 3), 256, 0, stream>>>(qa);

    attn5<<<dim3(BATCH * NHEAD * (SEQ / 128) * KSPLIT), 256, 0, stream>>>(
        qb16, kb16, vT16, em16, Xp16, Lp);

    combine_attn<<<dim3(NROWS * 8 / 256), 256, 0, stream>>>(Xp16, Lp, xb16);

    gemm_fin<<<dim3(DMODEL / 128, BATCH * SEQ / 128), 256, 0, stream>>>(
        xb16, WoT, bo, out);
}

// Round 3
// 231.658 us; speedup vs baseline: 1.0177x; 1.0177x over previous
//
#include <hip/hip_runtime.h>

#define SEQ    2048
#define DMODEL 512
#define NHEAD  8
#define HDIM   64
#define BATCH  4
#define NROWS  65536          // H*SEQ*BATCH scrambled q-rows
#define KSPLIT 2

#define LOG2E  1.4426950408889634f
#define QSCALE 0.18033688011112042f   // 0.125 * log2(e), folded into Q proj

typedef float f32x4  __attribute__((ext_vector_type(4)));
typedef float f32x16 __attribute__((ext_vector_type(16)));
typedef _Float16 h16x8 __attribute__((ext_vector_type(8)));
typedef _Float16 h16x2 __attribute__((ext_vector_type(2)));
typedef unsigned int u32x2 __attribute__((ext_vector_type(2)));

union U4H { uint4 u; h16x8 h; };
union U1H2 { unsigned int u; h16x2 h; };

// counted-vmcnt wait + raw barrier (do NOT use __syncthreads: it drains vmcnt(0))
#define WAITV(N) asm volatile("s_waitcnt vmcnt(" #N ")" ::: "memory")

static __device__ inline h16x2 pkrtz(float a, float b) {
    return __builtin_bit_cast(h16x2, __builtin_amdgcn_cvt_pkrtz(a, b));
}
static __device__ inline unsigned short f2h(float x) {
    _Float16 h = (_Float16)x;
    return __builtin_bit_cast(unsigned short, h);
}
// async 16B/lane global->LDS copy (lds base must be wave-uniform)
static __device__ inline void async_cp16(const void* g, void* l) {
    __builtin_amdgcn_global_load_lds(
        (const __attribute__((address_space(1))) unsigned int*)g,
        (__attribute__((address_space(3))) unsigned int*)l,
        16, 0, 0);
}

// ---------------------------------------------------------------------------
// Fused pre-pass (one dispatch, three independent jobs selected by block id):
//   [0,1024)        transpose-cast the four 512x512 weight mats -> f16 [n][k]
//   [1024,5120)     em = fp16(exp(mask)) permuted to the S^T C-layout order
//   [5120,11264)    fp32 -> fp16 cast of the three activation inputs
// ---------------------------------------------------------------------------
struct PrepArgs {
    const float *Wq, *Wk, *Wv, *Wo;
    unsigned short *WqT, *WkT, *WvT, *WoT;
    const float *mask; unsigned short *mp;
    const float *aq, *ak, *av;
    unsigned short *dq, *dk, *dv;
};

__global__ __launch_bounds__(256) void prepass(PrepArgs a) {
    const int bid = blockIdx.x;
    const int t = threadIdx.x;

    if (bid < 1024) {
        // ---- weight transpose-cast ----
        const int z = bid >> 8, y = (bid >> 4) & 15, x = bid & 15;
        const float* S; unsigned short* D;
        switch (z) {
            case 0: S = a.Wq; D = a.WqT; break;
            case 1: S = a.Wk; D = a.WkT; break;
            case 2: S = a.Wv; D = a.WvT; break;
            default: S = a.Wo; D = a.WoT; break;
        }
        __shared__ float T[32][33];
        const int r = t >> 3, c = (t & 7) * 4;
        const int k0 = x * 32, n0 = y * 32;
        float4 v = *(const float4*)&S[(size_t)(k0 + r) * DMODEL + n0 + c];
        T[r][c] = v.x; T[r][c + 1] = v.y; T[r][c + 2] = v.z; T[r][c + 3] = v.w;
        __syncthreads();
        ushort4 o;
        o.x = f2h(T[c + 0][r]); o.y = f2h(T[c + 1][r]);
        o.z = f2h(T[c + 2][r]); o.w = f2h(T[c + 3][r]);
        *(ushort4*)&D[(size_t)(n0 + r) * DMODEL + k0 + c] = o;
    } else if (bid < 1024 + 4096) {
        // ---- mask exp pre-pass ----
        int i = (bid - 1024) * 256 + t;             // float4 index
        int k = (i * 4) & (SEQ - 1);
        int q = (i * 4) >> 11;
        float4 v = ((const float4*)a.mask)[i];
        int kt = k >> 6, kl = k & 63;
        int mt = kl >> 5, g = (kl >> 3) & 3, hl = (kl >> 2) & 1;
        size_t base = ((size_t)kt * SEQ + q) * 64 + hl * 32 + mt * 16 + g * 4;
        ushort4 o;
        o.x = f2h(__builtin_amdgcn_exp2f(v.x * LOG2E));
        o.y = f2h(__builtin_amdgcn_exp2f(v.y * LOG2E));
        o.z = f2h(__builtin_amdgcn_exp2f(v.z * LOG2E));
        o.w = f2h(__builtin_amdgcn_exp2f(v.w * LOG2E));
        *(ushort4*)&a.mp[base] = o;
    } else {
        // ---- activation fp32 -> fp16 cast ----
        int u = bid - 5120;
        int z = u >> 11, blk = u & 2047;
        const float* S; unsigned short* D;
        switch (z) {
            case 0: S = a.aq; D = a.dq; break;
            case 1: S = a.ak; D = a.dk; break;
            default: S = a.av; D = a.dv; break;
        }
        size_t i = ((size_t)blk * 256 + t) * 8;
        float4 x = *(const float4*)&S[i];
        float4 y = *(const float4*)&S[i + 4];
        U1H2 p0, p1, p2, p3;
        p0.h = pkrtz(x.x, x.y); p1.h = pkrtz(x.z, x.w);
        p2.h = pkrtz(y.x, y.y); p3.h = pkrtz(y.z, y.w);
        *(uint4*)&D[i] = make_uint4(p0.u, p1.u, p2.u, p3.u);
    }
}

// ---------------------------------------------------------------------------
// GEMM core (f16 A): C[..][512] = A[..][512] @ Wt[512][512]^T + bias.
// 128x128 tile, BK=32, 256 thr = 4 waves, wave = 64m x 64n (4x4 MFMA 16x16x32).
// TRIPLE-buffered LDS + counted vmcnt + raw s_barrier: stage(p+2) issued in
// iter p, end-of-iter wait is vmcnt(4) (stage(p+2) stays in flight), so
// stage(p+1) has ~2 tiles of latency cover. vmcnt never drains to 0 mid-loop.
// Both-sides XOR chunk swizzle -> frag reads land in the free 2-way case.
// EPI: 0 = f32 row-major, 1 = f16 row-major, 2 = f16 transposed per-head to
//      vT[((b*8+h)*64+dv)*SEQ + key]
// ---------------------------------------------------------------------------
template <int EPI>
static __device__ inline void gemm_core16(
    const unsigned short* __restrict__ Ab, const unsigned short* __restrict__ Bt,
    const float* __restrict__ bias, void* __restrict__ Cout, float oscale,
    int bm, int bn)
{
    __shared__ __align__(16) unsigned short As[3][128 * 32];
    __shared__ __align__(16) unsigned short Bs[3][128 * 32];

    const int t = threadIdx.x;
    const int lane = t & 63, w = t >> 6;
    const int wm = w >> 1, wn = w & 1;
    const int c = lane & 15, quad = lane >> 4;
    const int srow = lane >> 2;                      // row within 16-row group
    const int sck  = (lane & 3) ^ ((lane >> 3) & 3); // swizzled source chunk

    f32x4 acc[4][4] = {};

    const int NT = DMODEL / 32;                      // 16 K-steps

    // prologue: stage tiles 0 and 1
    #pragma unroll
    for (int b2 = 0; b2 < 2; b2++) {
        #pragma unroll
        for (int i = 0; i < 2; i++) {
            int row = 32 * w + 16 * i + srow;
            async_cp16(Ab + (size_t)(bm + row) * DMODEL + b2 * 32 + sck * 8,
                       &As[b2][(32 * w + 16 * i) * 32]);
            async_cp16(Bt + (size_t)(bn + row) * DMODEL + b2 * 32 + sck * 8,
                       &Bs[b2][(32 * w + 16 * i) * 32]);
        }
    }
    WAITV(4);                               // stage(0) done; stage(1) in flight
    __builtin_amdgcn_s_barrier();

    const int slot8 = (quad ^ ((c >> 1) & 3)) * 8;

    int cur = 0;
    for (int p = 0; p < NT; p++) {
        // stage(p+2) into buf (cur+2)%3
        if (p + 2 < NT) {
            int nxt = cur + 2; if (nxt >= 3) nxt -= 3;
            int kn = (p + 2) * 32;
            #pragma unroll
            for (int i = 0; i < 2; i++) {
                int row = 32 * w + 16 * i + srow;
                async_cp16(Ab + (size_t)(bm + row) * DMODEL + kn + sck * 8,
                           &As[nxt][(32 * w + 16 * i) * 32]);
                async_cp16(Bt + (size_t)(bn + row) * DMODEL + kn + sck * 8,
                           &Bs[nxt][(32 * w + 16 * i) * 32]);
            }
        }
        U4H af[4], bf[4];
        #pragma unroll
        for (int mt = 0; mt < 4; mt++)
            af[mt].u = *(const uint4*)&As[cur][(wm * 64 + mt * 16 + c) * 32 + slot8];
        #pragma unroll
        for (int nt = 0; nt < 4; nt++)
            bf[nt].u = *(const uint4*)&Bs[cur][(wn * 64 + nt * 16 + c) * 32 + slot8];
        #pragma unroll
        for (int mt = 0; mt < 4; mt++)
            #pragma unroll
            for (int nt = 0; nt < 4; nt++)
                acc[mt][nt] = __builtin_amdgcn_mfma_f32_16x16x32_f16(
                    af[mt].h, bf[nt].h, acc[mt][nt], 0, 0, 0);
        // end-of-iter: ensure stage(p+1) landed; leave stage(p+2) in flight
        if (p + 1 < NT) {
            if (p + 2 < NT) { WAITV(4); } else { WAITV(0); }
            __builtin_amdgcn_s_barrier();
        }
        cur = cur + 1; if (cur >= 3) cur -= 3;
    }

    if (EPI == 2) {
        #pragma unroll
        for (int nt = 0; nt < 4; nt++) {
            int ng = bn + wn * 64 + nt * 16 + c;
            int h = ng >> 6, dv = ng & 63;
            float bv = bias[ng];
            #pragma unroll
            for (int mt = 0; mt < 4; mt++) {
                int mg0 = bm + wm * 64 + mt * 16 + quad * 4;
                int bb = mg0 >> 11, key0 = mg0 & (SEQ - 1);
                U1H2 lo, hi;
                lo.h = pkrtz(acc[mt][nt][0] + bv, acc[mt][nt][1] + bv);
                hi.h = pkrtz(acc[mt][nt][2] + bv, acc[mt][nt][3] + bv);
                *(uint2*)&((unsigned short*)Cout)[
                    ((size_t)(bb * NHEAD + h) * HDIM + dv) * SEQ + key0] =
                    make_uint2(lo.u, hi.u);
            }
        }
        return;
    }
    #pragma unroll
    for (int nt = 0; nt < 4; nt++) {
        int ng = bn + wn * 64 + nt * 16 + c;
        float bv = bias[ng];
        #pragma unroll
        for (int mt = 0; mt < 4; mt++) {
            #pragma unroll
            for (int r = 0; r < 4; r++) {
                int mg = bm + wm * 64 + mt * 16 + quad * 4 + r;
                float v = (acc[mt][nt][r] + bv) * oscale;
                if (EPI == 1)
                    ((unsigned short*)Cout)[(size_t)mg * DMODEL + ng] = f2h(v);
                else
                    ((float*)Cout)[(size_t)mg * DMODEL + ng] = v;
            }
        }
    }
}

struct QKVArgs {
    const unsigned short *A0, *A1, *A2;
    const unsigned short *W0, *W1, *W2;
    const float *b0, *b1, *b2;
    unsigned short *o0, *o1, *o2;
};

__global__ __launch_bounds__(256) void gemm_qkv(QKVArgs a) {
    if (blockIdx.z == 2)
        gemm_core16<2>(a.A2, a.W2, a.b2, a.o2, 1.0f, blockIdx.y * 128, blockIdx.x * 128);
    else if (blockIdx.z == 1)
        gemm_core16<1>(a.A1, a.W1, a.b1, a.o1, 1.0f, blockIdx.y * 128, blockIdx.x * 128);
    else
        gemm_core16<1>(a.A0, a.W0, a.b0, a.o0, QSCALE, blockIdx.y * 128, blockIdx.x * 128);
}

__global__ __launch_bounds__(256) void gemm_fin(
    const unsigned short* __restrict__ A, const unsigned short* __restrict__ W,
    const float* __restrict__ bias, float* __restrict__ C) {
    gemm_core16<0>(A, W, bias, C, 1.0f, blockIdx.y * 128, blockIdx.x * 128);
}

// ---------------------------------------------------------------------------
// Flash attention, 32x32x16 f16 MFMA, S^T trick, no-max softmax, K-SPLIT 2.
// Grid back to 3D (linear id = bh mod 8 -> K/V panels co-XCD; measured-good:
// FETCH ~ unique footprint). This revision: TRIPLE-buffered K/V staging with
// counted vmcnt + raw s_barrier (stage issued 2 tiles ahead; end-of-iter wait
// vmcnt(8) leaves em(p+1)+stage(p+2) in flight). em loads conditional and
// issue-ordered BEFORE stage so the vmcnt arithmetic is exact.
// ---------------------------------------------------------------------------
__global__ __launch_bounds__(256, 3) void attn5(
    const unsigned short* __restrict__ qb, const unsigned short* __restrict__ kb,
    const unsigned short* __restrict__ vT, const unsigned short* __restrict__ emp,
    unsigned short* __restrict__ Xp, float* __restrict__ Lp)
{
    __shared__ __align__(16) unsigned short Ks[3][64 * 64];
    __shared__ __align__(16) unsigned short Vs[3][64 * 64];

    const int t = threadIdx.x;            // 0..255
    const int lane = t & 63, w = t >> 6;  // 4 waves
    const int c32 = lane & 31, hl = lane >> 5;
    const int bh = blockIdx.x, b = bh >> 3, head = bh & 7;
    const int q0 = blockIdx.y * 128;
    const int split = blockIdx.z;         // keys [split*1024, split*1024+1024)
    const int qg = q0 + w * 32 + c32;
    const int NT = 1024 / 64;             // 16 K-tiles

    // hoisted Q B-frags (q pre-scaled by 0.125*log2e in projection)
    const unsigned short* qrow = qb + ((size_t)b * SEQ + qg) * DMODEL + head * HDIM;
    U4H Qf[4];
    #pragma unroll
    for (int s = 0; s < 4; s++)
        Qf[s].u = *(const uint4*)&qrow[s * 16 + hl * 8];

    const unsigned short* kgb = kb + (size_t)b * SEQ * DMODEL + head * HDIM
                              + (size_t)split * 1024 * DMODEL;
    const unsigned short* vgb = vT + (size_t)bh * HDIM * SEQ + split * 1024;

    // staging lane mapping: row-in-chunk = lane>>3, swizzled global chunk
    const int srow = lane >> 3;           // 0..7
    const int sch  = (lane & 7) ^ srow;   // logical feature/key chunk

    // em tile 0 (issue BEFORE staging: ordering matters for vmcnt counts)
    U4H e0, e1, e2, e3;
    {
        const unsigned short* mrow = emp + ((size_t)(split * 16) * SEQ + qg) * 64 + hl * 32;
        e0.u = *(const uint4*)&mrow[0];
        e1.u = *(const uint4*)&mrow[8];
        e2.u = *(const uint4*)&mrow[16];
        e3.u = *(const uint4*)&mrow[24];
    }

    // stage tiles 0 and 1 into buffers 0 and 1
    #pragma unroll
    for (int b2 = 0; b2 < 2; b2++) {
        int kq = b2 * 64;
        #pragma unroll
        for (int i = 0; i < 2; i++) {
            int row = w * 16 + i * 8 + srow;
            async_cp16(&kgb[(size_t)(kq + row) * DMODEL + sch * 8],
                       &Ks[b2][(w * 16 + i * 8) * 64]);
            async_cp16(&vgb[(size_t)row * SEQ + kq + sch * 8],
                       &Vs[b2][(w * 16 + i * 8) * 64]);
        }
    }
    WAITV(4);                    // Q+em(0)+stage(0) done; stage(1) in flight
    __builtin_amdgcn_s_barrier();

    f32x16 O0 = {}, O1 = {};
    float lsum = 0.f;
    const h16x2 one2 = {(_Float16)1.0f, (_Float16)1.0f};

    int cur = 0;
    for (int kt = 0; kt < NT; kt++) {
        // em prefetch for tile kt+1 (issued FIRST)
        U4H f0, f1, f2, f3;
        if (kt + 1 < NT) {
            const unsigned short* mrow =
                emp + ((size_t)(split * 16 + kt + 1) * SEQ + qg) * 64 + hl * 32;
            f0.u = *(const uint4*)&mrow[0];
            f1.u = *(const uint4*)&mrow[8];
            f2.u = *(const uint4*)&mrow[16];
            f3.u = *(const uint4*)&mrow[24];
        }

        // stage tile kt+2 into buffer (cur+2)%3
        if (kt + 2 < NT) {
            int nxt = cur + 2; if (nxt >= 3) nxt -= 3;
            int k0n = (kt + 2) * 64;
            #pragma unroll
            for (int i = 0; i < 2; i++) {
                int row = w * 16 + i * 8 + srow;
                async_cp16(&kgb[(size_t)(k0n + row) * DMODEL + sch * 8],
                           &Ks[nxt][(w * 16 + i * 8) * 64]);
                async_cp16(&vgb[(size_t)row * SEQ + k0n + sch * 8],
                           &Vs[nxt][(w * 16 + i * 8) * 64]);
            }
        }

        const unsigned short* Kp = Ks[cur];
        const unsigned short* Vp = Vs[cur];

        // ---- S^T = K.Q^T : 2 key-tiles x 4 feature-steps ----
        f32x16 S0 = {}, S1 = {};
        __builtin_amdgcn_s_setprio(1);
        #pragma unroll
        for (int s = 0; s < 4; s++) {
            int fc = 2 * s + hl;
            int sl = (fc ^ (c32 & 7)) * 8;
            U4H ka0, ka1;
            ka0.u = *(const uint4*)&Kp[c32 * 64 + sl];
            ka1.u = *(const uint4*)&Kp[(32 + c32) * 64 + sl];
            S0 = __builtin_amdgcn_mfma_f32_32x32x16_f16(ka0.h, Qf[s].h, S0, 0, 0, 0);
            S1 = __builtin_amdgcn_mfma_f32_32x32x16_f16(ka1.h, Qf[s].h, S1, 0, 0, 0);
        }
        __builtin_amdgcn_s_setprio(0);

        // ---- softmax: p = exp2(S) * em, f16 pack, l-accumulate via dot2 ----
        unsigned int Pf[4][4];
        #pragma unroll
        for (int mt = 0; mt < 2; mt++) {
            f32x16 S = mt ? S1 : S0;
            h16x8 ea = (mt ? e2 : e0).h;
            h16x8 eb = (mt ? e3 : e1).h;
            unsigned int u[4][2];
            #pragma unroll
            for (int jj = 0; jj < 8; jj++) {
                _Float16 exl = (jj < 4) ? ea[2 * jj]     : eb[2 * jj - 8];
                _Float16 exh = (jj < 4) ? ea[2 * jj + 1] : eb[2 * jj - 7];
                h16x2 ex = {exl, exh};
                h16x2 pk = pkrtz(__builtin_amdgcn_exp2f(S[2 * jj]),
                                 __builtin_amdgcn_exp2f(S[2 * jj + 1]));
                h16x2 pp = pk * ex;
#if __has_builtin(__builtin_amdgcn_fdot2)
                lsum = __builtin_amdgcn_fdot2(pp, one2, lsum, false);
#else
                lsum += (float)pp[0] + (float)pp[1];
#endif
                u[jj >> 1][jj & 1] = __builtin_bit_cast(unsigned int, pp);
            }
            // half-wave block exchange (C-layout -> PV B-operand layout)
#if __has_builtin(__builtin_amdgcn_permlane32_swap)
            u32x2 rA0 = __builtin_amdgcn_permlane32_swap(u[0][0], u[1][0], false, false);
            u32x2 rA1 = __builtin_amdgcn_permlane32_swap(u[0][1], u[1][1], false, false);
            u32x2 rB0 = __builtin_amdgcn_permlane32_swap(u[2][0], u[3][0], false, false);
            u32x2 rB1 = __builtin_amdgcn_permlane32_swap(u[2][1], u[3][1], false, false);
            Pf[2 * mt + 0][0] = rA0[0]; Pf[2 * mt + 0][1] = rA1[0];
            Pf[2 * mt + 0][2] = rA0[1]; Pf[2 * mt + 0][3] = rA1[1];
            Pf[2 * mt + 1][0] = rB0[0]; Pf[2 * mt + 1][1] = rB1[0];
            Pf[2 * mt + 1][2] = rB0[1]; Pf[2 * mt + 1][3] = rB1[1];
#else
            unsigned int sA0 = hl ? u[0][0] : u[1][0];
            unsigned int sA1 = hl ? u[0][1] : u[1][1];
            unsigned int sB0 = hl ? u[2][0] : u[3][0];
            unsigned int sB1 = hl ? u[2][1] : u[3][1];
            unsigned int rA0 = (unsigned)__shfl_xor((int)sA0, 32, 64);
            unsigned int rA1 = (unsigned)__shfl_xor((int)sA1, 32, 64);
            unsigned int rB0 = (unsigned)__shfl_xor((int)sB0, 32, 64);
            unsigned int rB1 = (unsigned)__shfl_xor((int)sB1, 32, 64);
            Pf[2 * mt + 0][0] = hl ? rA0 : u[0][0];
            Pf[2 * mt + 0][1] = hl ? rA1 : u[0][1];
            Pf[2 * mt + 0][2] = hl ? u[1][0] : rA0;
            Pf[2 * mt + 0][3] = hl ? u[1][1] : rA1;
            Pf[2 * mt + 1][0] = hl ? rB0 : u[2][0];
            Pf[2 * mt + 1][1] = hl ? rB1 : u[2][1];
            Pf[2 * mt + 1][2] = hl ? u[3][0] : rB0;
            Pf[2 * mt + 1][3] = hl ? u[3][1] : rB1;
#endif
        }

        // ---- O^T += V^T . P : 2 dv-tiles x 4 key-steps ----
        __builtin_amdgcn_s_setprio(1);
        #pragma unroll
        for (int s = 0; s < 4; s++) {
            int kc = 2 * s + hl;
            int sl = (kc ^ (c32 & 7)) * 8;
            U4H va0, va1, pu;
            va0.u = *(const uint4*)&Vp[c32 * 64 + sl];
            va1.u = *(const uint4*)&Vp[(32 + c32) * 64 + sl];
            pu.u = make_uint4(Pf[s][0], Pf[s][1], Pf[s][2], Pf[s][3]);
            O0 = __builtin_amdgcn_mfma_f32_32x32x16_f16(va0.h, pu.h, O0, 0, 0, 0);
            O1 = __builtin_amdgcn_mfma_f32_32x32x16_f16(va1.h, pu.h, O1, 0, 0, 0);
        }
        __builtin_amdgcn_s_setprio(0);

        // rotate em prefetch registers
        if (kt + 1 < NT) { e0 = f0; e1 = f1; e2 = f2; e3 = f3; }

        // end-of-iter: ensure stage(kt+1) landed; keep em(kt+1)+stage(kt+2)
        // in flight (4+4 -> vmcnt(8); tail: only em -> vmcnt(4))
        if (kt + 1 < NT) {
            if (kt + 2 < NT) { WAITV(8); } else { WAITV(4); }
            __builtin_amdgcn_s_barrier();
        }
        cur = cur + 1; if (cur >= 3) cur -= 3;
    }

    // ---- epilogue: combine lane-halves' l, store UNNORMALIZED f16 partial ----
    lsum += __shfl_xor(lsum, 32, 64);
    const size_t j = ((size_t)head * SEQ + qg) * BATCH + b;
    unsigned short* xr = Xp + ((size_t)split * NROWS + j) * HDIM;
    #pragma unroll
    for (int mt = 0; mt < 2; mt++) {
        f32x16 Ov = mt ? O1 : O0;
        #pragma unroll
        for (int g = 0; g < 4; g++) {
            U1H2 lo, hi;
            lo.h = pkrtz(Ov[g * 4 + 0], Ov[g * 4 + 1]);
            hi.h = pkrtz(Ov[g * 4 + 2], Ov[g * 4 + 3]);
            uint2 st = make_uint2(lo.u, hi.u);
            *(uint2*)&xr[mt * 32 + 8 * g + 4 * hl] = st;
        }
    }
    if (hl == 0) Lp[split * NROWS + j] = lsum;
}

// ---------------------------------------------------------------------------
// Combine K-split partials: xb[j][dv] = (Sum_r Xp[r][j][dv]) / (Sum_r L[r][j])
// ---------------------------------------------------------------------------
__global__ __launch_bounds__(256) void combine_attn(
    const unsigned short* __restrict__ Xp, const float* __restrict__ Lp,
    unsigned short* __restrict__ xb)
{
    int i = blockIdx.x * 256 + threadIdx.x;
    int j = i >> 3, dc = (i & 7) * 8;
    U4H a, b;
    a.u = *(const uint4*)&Xp[(size_t)j * HDIM + dc];
    b.u = *(const uint4*)&Xp[((size_t)NROWS + j) * HDIM + dc];
    float inv = 1.0f / (Lp[j] + Lp[NROWS + j]);
    U4H o;
    #pragma unroll
    for (int p = 0; p < 4; p++) {
        float s0 = ((float)a.h[2 * p]     + (float)b.h[2 * p])     * inv;
        float s1 = ((float)a.h[2 * p + 1] + (float)b.h[2 * p + 1]) * inv;
        h16x2 pk = pkrtz(s0, s1);
        o.h[2 * p] = pk[0]; o.h[2 * p + 1] = pk[1];
    }
    *(uint4*)&xb[(size_t)j * HDIM + dc] = o.u;
}

// ---------------------------------------------------------------------------
extern "C" void kernel_launch(void* const* d_in, const int* in_sizes, int n_in,
                              void* d_out, int out_size, void* d_ws, size_t ws_size,
                              hipStream_t stream) {
    const float* query = (const float*)d_in[0];
    const float* key_  = (const float*)d_in[1];
    const float* value = (const float*)d_in[2];
    const float* mask  = (const float*)d_in[3];
    const float* Wq = (const float*)d_in[4];
    const float* bq = (const float*)d_in[5];
    const float* Wk = (const float*)d_in[6];
    const float* bk = (const float*)d_in[7];
    const float* Wv = (const float*)d_in[8];
    const float* bv = (const float*)d_in[9];
    const float* Wo = (const float*)d_in[10];
    const float* bo = (const float*)d_in[11];
    float* out = (float*)d_out;

    const size_t NP = (size_t)BATCH * SEQ * DMODEL;   // 4194304
    unsigned short* ws   = (unsigned short*)d_ws;
    unsigned short* qb16 = ws;
    unsigned short* kb16 = qb16 + NP;
    unsigned short* vT16 = kb16 + NP;
    unsigned short* xb16 = vT16 + NP;
    unsigned short* em16 = xb16 + NP;                 // SEQ*SEQ f16
    unsigned short* Xp16 = em16 + (size_t)SEQ * SEQ;  // KSPLIT*NROWS*64 f16 = 2*NP
    unsigned short* WqT  = Xp16 + (size_t)KSPLIT * NROWS * HDIM;
    unsigned short* WkT  = WqT + DMODEL * DMODEL;
    unsigned short* WvT  = WkT + DMODEL * DMODEL;
    unsigned short* WoT  = WvT + DMODEL * DMODEL;
    float* Lp = (float*)(WoT + DMODEL * DMODEL);      // KSPLIT*NROWS f32

    // f16 casts of Q/K/V inputs live in regions that are dead until attn/combine:
    unsigned short* q16 = xb16;
    unsigned short* k16 = Xp16;
    unsigned short* v16 = Xp16 + NP;

    PrepArgs pa;
    pa.Wq = Wq; pa.Wk = Wk; pa.Wv = Wv; pa.Wo = Wo;
    pa.WqT = WqT; pa.WkT = WkT; pa.WvT = WvT; pa.WoT = WoT;
    pa.mask = mask; pa.mp = em16;
    pa.aq = query; pa.ak = key_; pa.av = value;
    pa.dq = q16; pa.dk = k16; pa.dv = v16;
    prepass<<<dim3(1024 + 4096 + 6144), 256, 0, stream>>>(pa);

    QKVArgs qa;
    qa.A0 = q16;  qa.A1 = k16;  qa.A2 = v16;
    qa.W0 = WqT;  qa.W1 = WkT;  qa.W2 = WvT;
    qa.b0 = bq;   qa.b1 = bk;   qa.b2 = bv;
    qa.o0 = qb16; qa.o1 = kb16; qa.o2 = vT16;   // V written transposed
    gemm_qkv<<<dim3(DMODEL / 128, BATCH * SEQ / 128, 3), 256, 0, stream>>>(qa);

    attn5<<<dim3(BATCH * NHEAD, SEQ / 128, KSPLIT), 256, 0, stream>>>(
        qb16, kb16, vT16, em16, Xp16, Lp);

    combine_attn<<<dim3(NROWS * 8 / 256), 256, 0, stream>>>(Xp16, Lp, xb16);

    gemm_fin<<<dim3(DMODEL / 128, BATCH * SEQ / 128), 256, 0, stream>>>(
        xb16, WoT, bo, out);
}